// Round 1
// baseline (270.459 us; speedup 1.0000x reference)
//
#include <hip/hip_runtime.h>

#define NCH 2048
#define HW 196
#define NB 64
#define NOUT 48    // 32 downconv rows + 8 fc2 rows (cols 2048..4095) + 8 fc1 rows (cols 0..2047)
#define NCHUNK 8
#define CPC (NCH / NCHUNK)     // 256 channels per block
#define KS_PER_BLK (CPC / 32)  // 8 K-steps of 32 channels
#define NT 13                  // N-tiles of 16 (208 >= 196)
#define MT 3                   // M-tiles of 16 (48 outputs)
#define TILE_F (32 * HW)       // 6272 floats per K-step tile (25088 B, contiguous in x)
#define TILE_V4 (TILE_F / 4)   // 1568 float4
#define SLAB (NT * NOUT * 16)  // 9984 floats per (b,chunk) blocked slab
#define SLAB4 (SLAB / 4)       // 2496 float4
#define NFRAG (KS_PER_BLK * MT * 64)  // 1536 a-fragments per block (24.5 KiB)
#define MAGIC 0x5ACE5ACEu

typedef __attribute__((ext_vector_type(8))) short bf16x8;
typedef __attribute__((ext_vector_type(4))) float f32x4;
typedef __attribute__((ext_vector_type(4))) int i32x4;

__device__ __forceinline__ short f2bf(float f) {   // fp32->bf16 RNE (weights)
    unsigned int u = __float_as_uint(f);
    u = u + 0x7fffu + ((u >> 16) & 1u);
    return (short)(u >> 16);
}

// Conv-phase LDS: double-buffered x tile + this block's pre-swizzled A fragments.
struct ConvSM {
    float ldsx[2][TILE_F];     // 2 x 25088 B
    bf16x8 afrag[NFRAG];       // 24576 B  -> total 74752 B (2 blocks/CU)
};
// Finish-phase LDS (reused via union; only chunk-0 blocks enter this phase).
struct FinSM {
    float Ts[NOUT * HW];
    float gmp[32];
    float score[8];
    float xo[8];
    float sal[HW];
    float logit[8];
};

// ---------------------------------------------------------------------------
// Single fused kernel (R8): build_afrag folded into per-block LDS build,
// finish folded in via per-batch release/acquire flag handshake.
// Rationale: per-kernel model says conv ~20us + finish ~8us + build ~3us,
// but measured 184us -> the cost is launch boundaries / dispatch stream,
// not any one kernel. 512 blocks @ 74.75KB LDS = exactly 2 blocks/CU
// co-resident, so the chunk-0 spin cannot deadlock.
// ---------------------------------------------------------------------------
__global__ __launch_bounds__(256) void wsl_fused(const float* __restrict__ x,
                                                 const float* __restrict__ down_w,
                                                 const float* __restrict__ down_b,
                                                 const float* __restrict__ fc_w,
                                                 const float* __restrict__ fc_b,
                                                 float* __restrict__ part,
                                                 unsigned int* __restrict__ flags,
                                                 float* __restrict__ out) {
    __shared__ union { ConvSM conv; FinSM fin; } sm;

    const int chunk = blockIdx.x;
    const int b = blockIdx.y;
    const int tid = threadIdx.x;
    const int wave = tid >> 6;
    const int lane = tid & 63;
    const int nsub = lane & 15;
    const int kq = lane >> 4;

    f32x4 acc[4][MT];
#pragma unroll
    for (int i = 0; i < 4; ++i)
#pragma unroll
        for (int m = 0; m < MT; ++m)
            acc[i][m] = (f32x4){0.f, 0.f, 0.f, 0.f};

    int pidx[4];
#pragma unroll
    for (int i = 0; i < 4; ++i) {
        int p = (wave + 4 * i) * 16 + nsub;
        pidx[i] = (p < HW) ? p : (HW - 1);   // clamp; junk cols ignored downstream
    }

    const float* xtile0 = x + ((size_t)b * NCH + (size_t)chunk * CPC) * HW;

    auto stage = [&](int ks, int bb) {
        const float* g = xtile0 + (size_t)ks * TILE_F;
#pragma unroll
        for (int r = 0; r < 7; ++r) {              // ceil(1568/256)
            int q = r * 256 + tid;
            if (q < TILE_V4) {
                __builtin_amdgcn_global_load_lds(
                    (const __attribute__((address_space(1))) unsigned int*)(g + (size_t)q * 4),
                    (__attribute__((address_space(3))) unsigned int*)(&sm.conv.ldsx[bb][(r * 256 + wave * 64) * 4]),
                    16, 0, 0);
            }
        }
    };

    stage(0, 0);

    // Build this block's A fragments into LDS (weights are L2/L3-hot after the
    // first touch; 1536 frags / 256 threads = 6 each, one-time cost).
    for (int f = tid; f < NFRAG; f += 256) {
        int fl = f & 63;
        int fi = f >> 6;              // 0..23
        int fmt = fi % MT;
        int fks = fi / MT;
        int o = fmt * 16 + (fl & 15);
        int c0 = (chunk * KS_PER_BLK + fks) * 32 + (fl >> 4) * 8;
        const float* wrow;
        if (o < 32)      wrow = down_w + (size_t)o * NCH + c0;
        else if (o < 40) wrow = fc_w + (size_t)(o - 32) * (2 * NCH) + NCH + c0;
        else             wrow = fc_w + (size_t)(o - 40) * (2 * NCH) + c0;
        bf16x8 v;
#pragma unroll
        for (int j = 0; j < 8; ++j)
            v[j] = f2bf(wrow[j]);
        sm.conv.afrag[f] = v;
    }

    for (int ks = 0; ks < KS_PER_BLK; ++ks) {
        __syncthreads();                  // barrier drains vmcnt -> tile ks (and afrag) visible
        if (ks + 1 < KS_PER_BLK) stage(ks + 1, (ks + 1) & 1);

        bf16x8 a0 = sm.conv.afrag[(ks * MT + 0) * 64 + lane];
        bf16x8 a1 = sm.conv.afrag[(ks * MT + 1) * 64 + lane];
        bf16x8 a2 = sm.conv.afrag[(ks * MT + 2) * 64 + lane];

        const float* base = &sm.conv.ldsx[ks & 1][kq * 8 * HW];
#pragma unroll
        for (int i = 0; i < 4; ++i) {
            const float* bp = base + pidx[i];
            unsigned int u[8];
#pragma unroll
            for (int j = 0; j < 8; ++j)
                u[j] = __float_as_uint(bp[j * HW]) + 0x8000u;  // round-half-up
            i32x4 bi;
            bi[0] = (int)__builtin_amdgcn_perm(u[1], u[0], 0x07060302u);
            bi[1] = (int)__builtin_amdgcn_perm(u[3], u[2], 0x07060302u);
            bi[2] = (int)__builtin_amdgcn_perm(u[5], u[4], 0x07060302u);
            bi[3] = (int)__builtin_amdgcn_perm(u[7], u[6], 0x07060302u);
            bf16x8 bv = __builtin_bit_cast(bf16x8, bi);
            acc[i][0] = __builtin_amdgcn_mfma_f32_16x16x32_bf16(a0, bv, acc[i][0], 0, 0, 0);
            acc[i][1] = __builtin_amdgcn_mfma_f32_16x16x32_bf16(a1, bv, acc[i][1], 0, 0, 0);
            acc[i][2] = __builtin_amdgcn_mfma_f32_16x16x32_bf16(a2, bv, acc[i][2], 0, 0, 0);
        }
    }

    // blocked store: part[b][chunk][nt][o][16], o = m*16 + kq*4 + r
    float* pb = part + (size_t)(b * NCHUNK + chunk) * SLAB;
#pragma unroll
    for (int i = 0; i < 4; ++i) {
        int nt = wave + 4 * i;
        if (nt < NT) {
            float* d = pb + nt * (NOUT * 16) + kq * 64 + nsub;
#pragma unroll
            for (int m = 0; m < MT; ++m)
#pragma unroll
                for (int r = 0; r < 4; ++r)
                    d[m * 256 + r * 16] = acc[i][m][r];
        }
    }

    // Release this block's slab: all threads fence (agent scope), block barrier
    // orders them before tid0's release-store of the flag.
    __threadfence();
    __syncthreads();
    if (tid == 0)
        __hip_atomic_store(&flags[b * NCHUNK + chunk], MAGIC,
                           __ATOMIC_RELEASE, __HIP_MEMORY_SCOPE_AGENT);

    if (chunk != 0) return;

    // --- finish phase: chunk-0 block of each batch waits for its 7 peers ---
    // ws is re-poisoned every iteration (the 392MiB fill in the profile), so
    // flags start != MAGIC. All 512 blocks are co-resident (2/CU) -> spin safe.
    if (tid >= 1 && tid < NCHUNK) {
        while (__hip_atomic_load(&flags[b * NCHUNK + tid],
                                 __ATOMIC_ACQUIRE, __HIP_MEMORY_SCOPE_AGENT) != MAGIC)
            __builtin_amdgcn_s_sleep(2);
    }
    __syncthreads();   // also fences the LDS union reuse (conv -> fin)

    {
        const float4* basep = (const float4*)(part + (size_t)b * NCHUNK * SLAB);
        for (int i4 = tid; i4 < SLAB4; i4 += 256) {
            float4 s = basep[i4];
#pragma unroll
            for (int ch = 1; ch < NCHUNK; ++ch) {
                float4 v = basep[(size_t)ch * SLAB4 + i4];
                s.x += v.x; s.y += v.y; s.z += v.z; s.w += v.w;
            }
            int nt = i4 / 192;               // NOUT*16/4
            int rem = i4 - nt * 192;
            int o = rem >> 2, ns4 = rem & 3;
            int p = nt * 16 + ns4 * 4;
            float vv[4] = {s.x, s.y, s.z, s.w};
#pragma unroll
            for (int q = 0; q < 4; ++q)
                if (p + q < HW) sm.fin.Ts[o * HW + p + q] = vv[q];
        }
    }
    __syncthreads();

    if (tid < 32) {
        float m = -1e30f;
        for (int p = 0; p < HW; ++p) m = fmaxf(m, sm.fin.Ts[tid * HW + p]);
        sm.fin.gmp[tid] = m + down_b[tid];
    }
    __syncthreads();

    if (tid < 8)
        sm.fin.score[tid] = 0.25f * (sm.fin.gmp[4 * tid] + sm.fin.gmp[4 * tid + 1] +
                                     sm.fin.gmp[4 * tid + 2] + sm.fin.gmp[4 * tid + 3]);
    __syncthreads();

    if (tid < 8) {
        float m = -1e30f;
        for (int k = 0; k < 8; ++k) m = fmaxf(m, sm.fin.score[k]);
        float se = 0.f;
        for (int k = 0; k < 8; ++k) se += expf(sm.fin.score[k] - m);
        float xo = sm.fin.score[tid] - m - logf(se);
        sm.fin.xo[tid] = xo;
        out[b * 8 + tid] = xo;
    }
    __syncthreads();

    if (tid < HW) {
        float s = 0.f;
#pragma unroll
        for (int k = 0; k < 8; ++k) {
            float bs = down_b[4 * k] + down_b[4 * k + 1] +
                       down_b[4 * k + 2] + down_b[4 * k + 3];
            float rs = sm.fin.Ts[(4 * k) * HW + tid] + sm.fin.Ts[(4 * k + 1) * HW + tid] +
                       sm.fin.Ts[(4 * k + 2) * HW + tid] + sm.fin.Ts[(4 * k + 3) * HW + tid] + bs;
            s += sm.fin.xo[k] * rs;
        }
        sm.fin.sal[tid] = s * (1.f / 32.f);
    }
    __syncthreads();

    if (tid < 8) {
        float t1 = 0.f, t2 = 0.f;
        for (int p = 0; p < HW; ++p) {
            t1 += sm.fin.Ts[(40 + tid) * HW + p];
            t2 += sm.fin.sal[p] * sm.fin.Ts[(32 + tid) * HW + p];
        }
        sm.fin.logit[tid] = (t1 + t2) * (1.f / 196.f) + fc_b[tid];
    }
    __syncthreads();

    if (tid < 8) {
        float m = -1e30f;
        for (int k = 0; k < 8; ++k) m = fmaxf(m, sm.fin.logit[k]);
        float se = 0.f;
        for (int k = 0; k < 8; ++k) se += expf(sm.fin.logit[k] - m);
        out[NB * 8 + b * 8 + tid] = sm.fin.logit[tid] - m - logf(se);
    }
}

extern "C" void kernel_launch(void* const* d_in, const int* in_sizes, int n_in,
                              void* d_out, int out_size, void* d_ws, size_t ws_size,
                              hipStream_t stream) {
    const float* x      = (const float*)d_in[0];
    const float* down_w = (const float*)d_in[1];
    const float* down_b = (const float*)d_in[2];
    const float* fc_w   = (const float*)d_in[3];
    const float* fc_b   = (const float*)d_in[4];
    float* out = (float*)d_out;

    float* part = (float*)d_ws;                                           // 20.4 MiB
    unsigned int* flags = (unsigned int*)((char*)d_ws + (size_t)NB * NCHUNK * SLAB * 4);  // 2 KiB

    wsl_fused<<<dim3(NCHUNK, NB), 256, 0, stream>>>(x, down_w, down_b, fc_w, fc_b,
                                                    part, flags, out);
}

// Round 2
// 185.432 us; speedup vs baseline: 1.4585x; 1.4585x over previous
//
#include <hip/hip_runtime.h>

#define NCH 2048
#define HW 196
#define NB 64
#define NOUT 48    // 32 downconv rows + 8 fc2 rows (cols 2048..4095) + 8 fc1 rows (cols 0..2047)
#define NCHUNK 8
#define CPC (NCH / NCHUNK)     // 256 channels per block
#define KS_PER_BLK (CPC / 32)  // 8 K-steps of 32 channels
#define KGTOT (NCH / 32)       // 64 global K-steps
#define NT 13                  // N-tiles of 16 (208 >= 196)
#define MT 3                   // M-tiles of 16 (48 outputs)
#define TILE_F (32 * HW)       // 6272 floats per K-step tile (25088 B, contiguous in x)
#define TILE_V4 (TILE_F / 4)   // 1568 float4
#define SLAB (NT * NOUT * 16)  // 9984 floats per (b,chunk) blocked slab
#define MAGICROW (NOUT * 16)   // 768

typedef __attribute__((ext_vector_type(8))) short bf16x8;
typedef __attribute__((ext_vector_type(4))) float f32x4;
typedef __attribute__((ext_vector_type(4))) int i32x4;

__device__ __forceinline__ short f2bf(float f) {   // fp32->bf16 RNE (weights)
    unsigned int u = __float_as_uint(f);
    u = u + 0x7fffu + ((u >> 16) & 1u);
    return (short)(u >> 16);
}

// ---------------------------------------------------------------------------
// Kernel 0: weights pre-swizzled to MFMA A-fragment order (R0-proven) + zero
// the per-batch completion counters (ws is poisoned every iteration).
// ---------------------------------------------------------------------------
__global__ void build_afrag(const float* __restrict__ down_w,
                            const float* __restrict__ fc_w,
                            bf16x8* __restrict__ afrag,
                            unsigned int* __restrict__ cnt) {
    int t = blockIdx.x * 256 + threadIdx.x;        // 64*3*64 = 12288
    if (blockIdx.x == 0 && threadIdx.x < NB) cnt[threadIdx.x] = 0;
    if (t >= KGTOT * MT * 64) return;
    int lane = t & 63;
    int frag = t >> 6;
    int mt = frag % MT;
    int kg = frag / MT;
    int o = mt * 16 + (lane & 15);
    int cbase = kg * 32 + (lane >> 4) * 8;
    bf16x8 v;
#pragma unroll
    for (int j = 0; j < 8; ++j) {
        int c = cbase + j;
        float w;
        if (o < 32)      w = down_w[o * NCH + c];
        else if (o < 40) w = fc_w[(o - 32) * (2 * NCH) + NCH + c];
        else             w = fc_w[(o - 40) * (2 * NCH) + c];
        v[j] = f2bf(w);
    }
    afrag[frag * 64 + lane] = v;
}

// Finish-phase LDS (reused via union with the conv x-tile buffer).
struct FinSM {
    float Ts[NOUT * HW];   // 37632 B
    float red[256];
    float gmp[32];
    float score[8];
    float xo[8];
    float sal[HW];
    float logit[8];
};

// ---------------------------------------------------------------------------
// Kernel 1 (R9): conv (R0-proven structure, 3 blocks/CU) + last-block finish.
// Cross-XCD discipline WITHOUT fences: part is written with relaxed
// agent-scope stores (sc1 -> coherence point, no dirty L2 lines anywhere) and
// read back by the finisher with relaxed agent-scope loads. The handshake is
// ONE relaxed agent fetch_add per block; only the 64 finisher blocks do an
// acquire (cheap, and belt-and-braces given sc1 loads). No threadfence, no
// spin -> none of R1's 512 L2-writeback / 448-spinner invalidate storms.
// ---------------------------------------------------------------------------
__global__ __launch_bounds__(256) void conv_fin(const float* __restrict__ x,
                                                const bf16x8* __restrict__ afrag,
                                                const float* __restrict__ down_b,
                                                const float* __restrict__ fc_b,
                                                float* __restrict__ part,
                                                unsigned int* __restrict__ cnt,
                                                float* __restrict__ out) {
    __shared__ union {
        float ldsx[2][TILE_F];   // 50176 B -> 3 blocks/CU (same as R0 conv)
        FinSM fin;
    } sm;
    __shared__ int lastS;

    const int chunk = blockIdx.x;
    const int b = blockIdx.y;
    const int tid = threadIdx.x;
    const int wave = tid >> 6;
    const int lane = tid & 63;
    const int nsub = lane & 15;
    const int kq = lane >> 4;

    f32x4 acc[4][MT];
#pragma unroll
    for (int i = 0; i < 4; ++i)
#pragma unroll
        for (int m = 0; m < MT; ++m)
            acc[i][m] = (f32x4){0.f, 0.f, 0.f, 0.f};

    int pidx[4];
#pragma unroll
    for (int i = 0; i < 4; ++i) {
        int p = (wave + 4 * i) * 16 + nsub;
        pidx[i] = (p < HW) ? p : (HW - 1);   // clamp; junk cols skipped in decode
    }

    const float* xtile0 = x + ((size_t)b * NCH + (size_t)chunk * CPC) * HW;

    auto stage = [&](int ks, int bb) {
        const float* g = xtile0 + (size_t)ks * TILE_F;
#pragma unroll
        for (int r = 0; r < 7; ++r) {              // ceil(1568/256)
            int q = r * 256 + tid;
            if (q < TILE_V4) {
                __builtin_amdgcn_global_load_lds(
                    (const __attribute__((address_space(1))) unsigned int*)(g + (size_t)q * 4),
                    (__attribute__((address_space(3))) unsigned int*)(&sm.ldsx[bb][(r * 256 + wave * 64) * 4]),
                    16, 0, 0);
            }
        }
    };

    stage(0, 0);

    for (int ks = 0; ks < KS_PER_BLK; ++ks) {
        __syncthreads();                  // barrier drains vmcnt -> tile ks visible
        if (ks + 1 < KS_PER_BLK) stage(ks + 1, (ks + 1) & 1);

        const int kg = chunk * KS_PER_BLK + ks;
        bf16x8 a0 = afrag[(kg * MT + 0) * 64 + lane];
        bf16x8 a1 = afrag[(kg * MT + 1) * 64 + lane];
        bf16x8 a2 = afrag[(kg * MT + 2) * 64 + lane];

        const float* base = &sm.ldsx[ks & 1][kq * 8 * HW];
#pragma unroll
        for (int i = 0; i < 4; ++i) {
            const float* bp = base + pidx[i];
            unsigned int u[8];
#pragma unroll
            for (int j = 0; j < 8; ++j)
                u[j] = __float_as_uint(bp[j * HW]) + 0x8000u;  // round-half-up
            i32x4 bi;
            bi[0] = (int)__builtin_amdgcn_perm(u[1], u[0], 0x07060302u);
            bi[1] = (int)__builtin_amdgcn_perm(u[3], u[2], 0x07060302u);
            bi[2] = (int)__builtin_amdgcn_perm(u[5], u[4], 0x07060302u);
            bi[3] = (int)__builtin_amdgcn_perm(u[7], u[6], 0x07060302u);
            bf16x8 bv = __builtin_bit_cast(bf16x8, bi);
            acc[i][0] = __builtin_amdgcn_mfma_f32_16x16x32_bf16(a0, bv, acc[i][0], 0, 0, 0);
            acc[i][1] = __builtin_amdgcn_mfma_f32_16x16x32_bf16(a1, bv, acc[i][1], 0, 0, 0);
            acc[i][2] = __builtin_amdgcn_mfma_f32_16x16x32_bf16(a2, bv, acc[i][2], 0, 0, 0);
        }
    }

    // blocked store: part[b][chunk][nt][o][16], o = m*16 + kq*4 + r.
    // Relaxed agent-scope stores -> sc1 (coherence point), readable cross-XCD
    // by plain relaxed agent loads with no fence.
    float* pb = part + (size_t)(b * NCHUNK + chunk) * SLAB;
#pragma unroll
    for (int i = 0; i < 4; ++i) {
        int nt = wave + 4 * i;
        if (nt < NT) {
            float* d = pb + nt * MAGICROW + kq * 64 + nsub;
#pragma unroll
            for (int m = 0; m < MT; ++m)
#pragma unroll
                for (int r = 0; r < 4; ++r)
                    __hip_atomic_store(&d[m * 256 + r * 16], acc[i][m][r],
                                       __ATOMIC_RELAXED, __HIP_MEMORY_SCOPE_AGENT);
        }
    }

    __syncthreads();   // each wave drains its own vmcnt before s_barrier -> all slab stores complete
    if (tid == 0) {
        unsigned int old = __hip_atomic_fetch_add(&cnt[b], 1u,
                                                  __ATOMIC_RELAXED, __HIP_MEMORY_SCOPE_AGENT);
        int last = (old == NCHUNK - 1);
        if (last)   // acquire only on the 64 finishers (orders the part reads)
            (void)__hip_atomic_load(&cnt[b], __ATOMIC_ACQUIRE, __HIP_MEMORY_SCOPE_AGENT);
        lastS = last;
    }
    __syncthreads();
    if (!lastS) return;

    // --- finish phase: this block is the last of batch b's 8 chunk blocks ---
    {
        float* basep = part + (size_t)b * NCHUNK * SLAB;
        for (int idx = tid; idx < SLAB; idx += 256) {
            float s = 0.f;
#pragma unroll
            for (int ch = 0; ch < NCHUNK; ++ch)
                s += __hip_atomic_load(&basep[(size_t)ch * SLAB + idx],
                                       __ATOMIC_RELAXED, __HIP_MEMORY_SCOPE_AGENT);
            int nt = idx / MAGICROW;
            int rem = idx - nt * MAGICROW;
            int o = rem >> 4, ns = rem & 15;
            int p = nt * 16 + ns;
            if (p < HW) sm.fin.Ts[o * HW + p] = s;
        }
    }
    __syncthreads();

    {   // GMP: 8 threads per output row (parallelized serial chain)
        int o = tid >> 3, s8 = tid & 7;
        float m = -1e30f;
        for (int p = s8; p < HW; p += 8) m = fmaxf(m, sm.fin.Ts[o * HW + p]);
        sm.fin.red[tid] = m;
    }
    __syncthreads();
    if (tid < 32) {
        float m = sm.fin.red[tid * 8];
#pragma unroll
        for (int j = 1; j < 8; ++j) m = fmaxf(m, sm.fin.red[tid * 8 + j]);
        sm.fin.gmp[tid] = m + down_b[tid];
    }
    __syncthreads();

    if (tid < 8)
        sm.fin.score[tid] = 0.25f * (sm.fin.gmp[4 * tid] + sm.fin.gmp[4 * tid + 1] +
                                     sm.fin.gmp[4 * tid + 2] + sm.fin.gmp[4 * tid + 3]);
    __syncthreads();

    if (tid < 8) {
        float m = -1e30f;
        for (int k = 0; k < 8; ++k) m = fmaxf(m, sm.fin.score[k]);
        float se = 0.f;
        for (int k = 0; k < 8; ++k) se += expf(sm.fin.score[k] - m);
        float xo = sm.fin.score[tid] - m - logf(se);
        sm.fin.xo[tid] = xo;
        out[b * 8 + tid] = xo;
    }
    __syncthreads();

    if (tid < HW) {
        float s = 0.f;
#pragma unroll
        for (int k = 0; k < 8; ++k) {
            float bs = down_b[4 * k] + down_b[4 * k + 1] +
                       down_b[4 * k + 2] + down_b[4 * k + 3];
            float rs = sm.fin.Ts[(4 * k) * HW + tid] + sm.fin.Ts[(4 * k + 1) * HW + tid] +
                       sm.fin.Ts[(4 * k + 2) * HW + tid] + sm.fin.Ts[(4 * k + 3) * HW + tid] + bs;
            s += sm.fin.xo[k] * rs;
        }
        sm.fin.sal[tid] = s * (1.f / 32.f);
    }
    __syncthreads();

    {   // logits: 32 threads per class (parallelized serial chain)
        int c = tid >> 5, s32 = tid & 31;
        float t = 0.f;
        for (int p = s32; p < HW; p += 32)
            t += sm.fin.Ts[(40 + c) * HW + p] + sm.fin.sal[p] * sm.fin.Ts[(32 + c) * HW + p];
        sm.fin.red[tid] = t;
    }
    __syncthreads();
    if (tid < 8) {
        float t = 0.f;
#pragma unroll
        for (int j = 0; j < 32; ++j) t += sm.fin.red[tid * 32 + j];
        sm.fin.logit[tid] = t * (1.f / 196.f) + fc_b[tid];
    }
    __syncthreads();

    if (tid < 8) {
        float m = -1e30f;
        for (int k = 0; k < 8; ++k) m = fmaxf(m, sm.fin.logit[k]);
        float se = 0.f;
        for (int k = 0; k < 8; ++k) se += expf(sm.fin.logit[k] - m);
        out[NB * 8 + b * 8 + tid] = sm.fin.logit[tid] - m - logf(se);
    }
}

extern "C" void kernel_launch(void* const* d_in, const int* in_sizes, int n_in,
                              void* d_out, int out_size, void* d_ws, size_t ws_size,
                              hipStream_t stream) {
    const float* x      = (const float*)d_in[0];
    const float* down_w = (const float*)d_in[1];
    const float* down_b = (const float*)d_in[2];
    const float* fc_w   = (const float*)d_in[3];
    const float* fc_b   = (const float*)d_in[4];
    float* out = (float*)d_out;

    bf16x8* afrag = (bf16x8*)d_ws;                                        // 192 KiB
    float* part = (float*)((char*)d_ws + (size_t)KGTOT * MT * 64 * 16);   // 20.4 MiB
    unsigned int* cnt = (unsigned int*)((char*)part + (size_t)NB * NCHUNK * SLAB * 4);  // 256 B

    build_afrag<<<(KGTOT * MT * 64 + 255) / 256, 256, 0, stream>>>(down_w, fc_w, afrag, cnt);
    conv_fin<<<dim3(NCHUNK, NB), 256, 0, stream>>>(x, afrag, down_b, fc_b, part, cnt, out);
}